// Round 16
// baseline (55.299 us; speedup 1.0000x reference)
//
#include <hip/hip_runtime.h>
#include <hip/hip_bf16.h>
#include <stdint.h>

typedef unsigned short u16;
typedef __attribute__((ext_vector_type(8))) short bf16x8;
typedef __attribute__((ext_vector_type(4))) float f32x4;
typedef __attribute__((ext_vector_type(2))) float f32x2;
typedef __attribute__((ext_vector_type(4))) unsigned int u32x4;
typedef __attribute__((ext_vector_type(2))) unsigned int u32x2;

#define NTOK 4096
#define NT32 32   // 4096 / 128 t2-tiles

#if __has_builtin(__builtin_amdgcn_exp2f)
#define EXP2F __builtin_amdgcn_exp2f
#else
#define EXP2F exp2f
#endif

__device__ __forceinline__ f32x4 MFMA(bf16x8 a, bf16x8 b, f32x4 c) {
    return __builtin_amdgcn_mfma_f32_16x16x32_bf16(a, b, c, 0, 0, 0);
}

// packed f32->bf16 (D.lo = bf16(a), D.hi = bf16(b))
__device__ __forceinline__ uint32_t pk_bf16(float a, float b) {
    uint32_t d;
    asm("v_cvt_pk_bf16_f32 %0, %1, %2" : "=v"(d) : "v"(a), "v"(b));
    return d;
}

// truncation hi/lo split of 8 floats into two bf16x8 fragments
__device__ __forceinline__ void hilo_pack8(const float* v, bf16x8* h, bf16x8* l) {
    union { uint32_t u[4]; bf16x8 b; } H, L;
#pragma unroll
    for (int m = 0; m < 4; ++m) {
        const uint32_t ua = __float_as_uint(v[2*m]);
        const uint32_t ub = __float_as_uint(v[2*m+1]);
        const float la = v[2*m]   - __uint_as_float(ua & 0xffff0000u);
        const float lb = v[2*m+1] - __uint_as_float(ub & 0xffff0000u);
        H.u[m] = (ua >> 16) | (ub & 0xffff0000u);
        L.u[m] = (__float_as_uint(la) >> 16) | (__float_as_uint(lb) & 0xffff0000u);
    }
    *h = H.b; *l = L.b;
}

// ---------------------------------------------------------------------------
// k_qkv: QKV projection via MFMA (w,x hi/lo 3-term) + repack through LDS.
// 512-thread blocks (grid 512 unchanged): 8 waves = 4 o-ranges x 2
// token-halves -> 16 waves/CU (was 8). Same index formulas, tt = th*2+tt2.
// Phase-2 repack redistributed: 1 unit/thread (Q, K), 2 units/thread (V).
// ---------------------------------------------------------------------------
__global__ __launch_bounds__(512) void k_qkv(
    const float* __restrict__ x, const float* __restrict__ wqkv, const float* __restrict__ bqkv,
    u16* __restrict__ Qp, u16* __restrict__ Kp, u16* __restrict__ Vp)
{
    __shared__ float qt_lds[64 * 194];
    const int blk = blockIdx.x;
    const int b   = blk >> 6;
    const int tb  = (blk & 63) << 6;
    const int tid = threadIdx.x;       // 0..511
    const int lane = tid & 63;
    const int wv8 = __builtin_amdgcn_readfirstlane(tid >> 6);  // 0..7
    const int wq  = wv8 & 3;           // output subrange
    const int th  = wv8 >> 2;          // token half
    const int r   = lane & 15;
    const int g   = lane >> 4;
    const int o0  = wq * 48;

    bf16x8 wh[3][2], wl[3][2];
#pragma unroll
    for (int oi = 0; oi < 3; ++oi)
#pragma unroll
        for (int ks = 0; ks < 2; ++ks) {
            const float* wp = wqkv + (size_t)(o0 + oi*16 + r) * 64 + ks*32 + g*8;
            float wv8f[8];
            *(f32x4*)(wv8f)     = *(const f32x4*)(wp);
            *(f32x4*)(wv8f + 4) = *(const f32x4*)(wp + 4);
            hilo_pack8(wv8f, &wh[oi][ks], &wl[oi][ks]);
        }

    f32x4 acc[3][2];
#pragma unroll
    for (int oi = 0; oi < 3; ++oi)
#pragma unroll
        for (int tt2 = 0; tt2 < 2; ++tt2) acc[oi][tt2] = 0.f;

#pragma unroll
    for (int tt2 = 0; tt2 < 2; ++tt2) {
        const int tt = th*2 + tt2;
        bf16x8 xh[2], xl[2];
#pragma unroll
        for (int ks = 0; ks < 2; ++ks) {
            float xv[8];
#pragma unroll
            for (int j = 0; j < 8; ++j)
                xv[j] = x[(size_t)(b*64 + ks*32 + g*8 + j) * NTOK + tb + tt*16 + r];
            hilo_pack8(xv, &xh[ks], &xl[ks]);
        }
#pragma unroll
        for (int oi = 0; oi < 3; ++oi) {
            f32x4 a = acc[oi][tt2];
            a = MFMA(wh[oi][0], xh[0], a);
            a = MFMA(wh[oi][1], xh[1], a);
            a = MFMA(wl[oi][0], xh[0], a);
            a = MFMA(wl[oi][1], xh[1], a);
            a = MFMA(wh[oi][0], xl[0], a);
            a = MFMA(wh[oi][1], xl[1], a);
            acc[oi][tt2] = a;
        }
    }

#pragma unroll
    for (int oi = 0; oi < 3; ++oi)
#pragma unroll
        for (int tt2 = 0; tt2 < 2; ++tt2)
#pragma unroll
            for (int i = 0; i < 4; ++i)
                qt_lds[((th*2 + tt2)*16 + r) * 194 + o0 + oi*16 + g*4 + i] = acc[oi][tt2][i];
    __syncthreads();

    const float SC = 0.18033688011112042f;  // (1/8) * log2(e)

    // ---- Q pack: 1 unit/thread: t = tid>>3, c0 = (tid&7)*8 ----
    {
        const int t = tid >> 3, c0 = (tid & 7) * 8;
        float v[8], bq[8];
#pragma unroll
        for (int m = 0; m < 4; ++m)
            *(f32x2*)(v + 2*m) = *(const f32x2*)&qt_lds[t*194 + c0 + 2*m];
        *(f32x4*)(bq)     = *(const f32x4*)(bqkv + c0);
        *(f32x4*)(bq + 4) = *(const f32x4*)(bqkv + c0 + 4);
        u32x4 P;
#pragma unroll
        for (int m = 0; m < 4; ++m)
            P[m] = pk_bf16((v[2*m] + bq[2*m]) * SC, (v[2*m+1] + bq[2*m+1]) * SC);
        *(u32x4*)(Qp + ((size_t)(b * NTOK + tb + t)) * 64 + c0) = P;
    }

    // ---- K pack: 1 unit/thread: t = tid>>3, ks = (tid>>2)&1, gk = tid&3 ----
    {
        const int t  = tid >> 3;
        const int ks = (tid >> 2) & 1;
        const int gk = tid & 3;
        const int cb0 = 64 + ks*32 + gk*8;
        float v[8];
#pragma unroll
        for (int m = 0; m < 4; ++m)
            *(f32x2*)(v + 2*m) = *(const f32x2*)&qt_lds[t*194 + cb0 + 2*m];
        u32x4 P;
#pragma unroll
        for (int m = 0; m < 4; ++m)
            P[m] = pk_bf16(v[2*m] + bqkv[cb0 + 2*m], v[2*m+1] + bqkv[cb0 + 2*m+1]);
        const int tg = tb + t;
        size_t kbase = (size_t)b * 262144 + ((size_t)(tg >> 4) * 2 + ks) * 512 + gk*128 + (t & 15) * 8;
        *(u32x4*)(Kp + kbase) = P;
    }

    // ---- V pack: 2 units/thread: tq = m*8 + (tid>>6), cb = (tid>>4)&3, r2 = tid&15 ----
    {
        const int cb = (tid >> 4) & 3;
        const int r2 = tid & 15;
        const float bv = bqkv[128 + cb*16 + r2];
        const int T = (blk & 63) >> 1;
        const int halfb = blk & 1;
#pragma unroll
        for (int m = 0; m < 2; ++m) {
            const int tq = m * 8 + (tid >> 6);  // 0..15
            float v[4];
#pragma unroll
            for (int jj = 0; jj < 4; ++jj)
                v[jj] = qt_lds[(tq*4 + jj)*194 + 128 + cb*16 + r2] + bv;
            const int t = tq * 4;
            const int wtr = halfb*2 + (t >> 5);
            const int sti = (t >> 4) & 1;
            const int g2  = (t >> 2) & 3;
            u32x2 W;
            W[0] = pk_bf16(v[0], v[1]);
            W[1] = pk_bf16(v[2], v[3]);
            size_t vbase = (size_t)b * 262144 +
                           (((size_t)T * 4 + wtr) * 4 + cb) * 512 + (g2*16 + r2) * 8 + sti * 4;
            *(u32x2*)(Vp + vbase) = W;
        }
    }
}

// ---------------------------------------------------------------------------
// k_attn: VERBATIM R14 (passed, 41.3 us, absmax 0.03125). K+V A/B register
// double-buffer with MFMA-ONES lacc at the permissive (256,2) bound.
// NOTE (R13/R15 lesson): K-dbuf combined with VALU lpart accumulation
// produced NaN twice — do not reintroduce that pair.
// ---------------------------------------------------------------------------
__global__ __launch_bounds__(256, 2) void k_attn(
    const u16* __restrict__ Qp, const u16* __restrict__ Kp, const u16* __restrict__ Vp,
    const float* __restrict__ wout, const float* __restrict__ bout,
    const float* __restrict__ x, float* __restrict__ out)
{
    __shared__ float larr[4][64];
    __shared__ float otbuf[2][64 * 67];
    const int hw  = blockIdx.x;
    const int b   = hw & 7;        // batch -> XCD pinning
    const int qt  = hw >> 3;       // 0..63
    const int tid = threadIdx.x;
    const int lane = tid & 63;
    const int wt2 = tid >> 6;      // t2-slice 0..3
    const int r   = lane & 15;
    const int g   = lane >> 4;
    const int row0 = qt * 64;

    // Q fragments (B operand), rows row0 + rt*16 + r, rt = 0..3
    bf16x8 qh[4][2];
#pragma unroll
    for (int rt = 0; rt < 4; ++rt) {
        const size_t qoff = ((size_t)(b * NTOK + row0 + rt*16 + r)) * 64 + g * 8;
        qh[rt][0] = *(const bf16x8*)(Qp + qoff);
        qh[rt][1] = *(const bf16x8*)(Qp + qoff + 32);
    }

    // per-wave K/V fragment bases (tile stride 8192 elems = 16 KB)
    const u16* kbase = Kp + (size_t)b * 262144 + wt2 * 2048 + (size_t)lane * 8;
    const u16* vbase = Vp + (size_t)b * 262144 + wt2 * 2048 + (size_t)lane * 8;

    // ones B-fragment for row-sum MFMA
    bf16x8 ONES;
#pragma unroll
    for (int j = 0; j < 8; ++j) ONES[j] = (short)0x3F80;

    f32x4 oacc[4][4];
#pragma unroll
    for (int rt = 0; rt < 4; ++rt)
#pragma unroll
        for (int cb = 0; cb < 4; ++cb) oacc[rt][cb] = 0.f;
    f32x4 lacc[4];
#pragma unroll
    for (int rt = 0; rt < 4; ++rt) lacc[rt] = 0.f;

    // preload K and V for tiles 0 (A) and 1 (B)
    bf16x8 kA[2][2], kB[2][2], vA[4], vB[4];
#pragma unroll
    for (int sti = 0; sti < 2; ++sti)
#pragma unroll
        for (int ks = 0; ks < 2; ++ks) {
            kA[sti][ks] = *(const bf16x8*)(kbase + (size_t)0*8192 + sti*1024 + ks*512);
            kB[sti][ks] = *(const bf16x8*)(kbase + (size_t)1*8192 + sti*1024 + ks*512);
        }
#pragma unroll
    for (int cb = 0; cb < 4; ++cb) {
        vA[cb] = *(const bf16x8*)(vbase + (size_t)0*8192 + cb*512);
        vB[cb] = *(const bf16x8*)(vbase + (size_t)1*8192 + cb*512);
    }

    auto halfrt = [&](bf16x8 (&kb)[2][2], bf16x8 (&vf)[4], int rt0) {
        // QK^T for row-tiles rt0, rt0+1 (8 MFMA)
        f32x4 s[2][2];
        __builtin_amdgcn_s_setprio(1);
#pragma unroll
        for (int rr = 0; rr < 2; ++rr)
#pragma unroll
            for (int sti = 0; sti < 2; ++sti) {
                f32x4 a = {0.f, 0.f, 0.f, 0.f};
                a = MFMA(kb[sti][0], qh[rt0 + rr][0], a);
                a = MFMA(kb[sti][1], qh[rt0 + rr][1], a);
                s[rr][sti] = a;
            }
        __builtin_amdgcn_s_setprio(0);

        // fixed-shift softmax + PV + l for the pair
#pragma unroll
        for (int rr = 0; rr < 2; ++rr) {
            const int rt = rt0 + rr;
            float p[8];
#pragma unroll
            for (int sti = 0; sti < 2; ++sti)
#pragma unroll
                for (int i = 0; i < 4; ++i)
                    p[sti*4 + i] = EXP2F(s[rr][sti][i]);
            union { uint32_t u[4]; bf16x8 b; } PA;
#pragma unroll
            for (int m = 0; m < 4; ++m) PA.u[m] = pk_bf16(p[2*m], p[2*m+1]);
            __builtin_amdgcn_s_setprio(1);
#pragma unroll
            for (int cb = 0; cb < 4; ++cb)
                oacc[rt][cb] = MFMA(PA.b, vf[cb], oacc[rt][cb]);
            lacc[rt] = MFMA(PA.b, ONES, lacc[rt]);
            __builtin_amdgcn_s_setprio(0);
        }
    };

    auto body = [&](bf16x8 (&kb)[2][2], bf16x8 (&vb)[4], int Tp) {
        halfrt(kb, vb, 0);
        halfrt(kb, vb, 2);

        // prefetch K and V for tile Tp into the register sets just consumed
        // (issued here, consumed one full body later -> latency hidden)
        const u16* kp = kbase + (size_t)Tp * 8192;
        const u16* vp = vbase + (size_t)Tp * 8192;
#pragma unroll
        for (int sti = 0; sti < 2; ++sti)
#pragma unroll
            for (int ks = 0; ks < 2; ++ks)
                kb[sti][ks] = *(const bf16x8*)(kp + sti*1024 + ks*512);
#pragma unroll
        for (int cb = 0; cb < 4; ++cb)
            vb[cb] = *(const bf16x8*)(vp + cb*512);
    };

    for (int T = 0; T < NT32; T += 2) {
        const int TpA = (T + 2 < NT32) ? T + 2 : NT32 - 1;
        const int TpB = (T + 3 < NT32) ? T + 3 : NT32 - 1;
        body(kA, vA, TpA);
        body(kB, vB, TpB);
    }

    // ---- epilogue: 4-way slice merge (plain sums; shift-exact softmax) ----
    if (r == 0) {
#pragma unroll
        for (int rt = 0; rt < 4; ++rt)
#pragma unroll
            for (int i = 0; i < 4; ++i)
                larr[wt2][rt*16 + g*4 + i] = lacc[rt][i];
    }

    // accumulate raw O partials (64 rows x 64 cols): wt2 0/1 write, 2/3 add
    if (wt2 < 2) {
        float* ob = otbuf[wt2];
#pragma unroll
        for (int rt = 0; rt < 4; ++rt)
#pragma unroll
            for (int cb = 0; cb < 4; ++cb)
#pragma unroll
                for (int i = 0; i < 4; ++i)
                    ob[(rt*16 + g*4 + i)*67 + cb*16 + r] = oacc[rt][cb][i];
    }
    __syncthreads();
    if (wt2 >= 2) {
        float* ob = otbuf[wt2 - 2];
#pragma unroll
        for (int rt = 0; rt < 4; ++rt)
#pragma unroll
            for (int cb = 0; cb < 4; ++cb)
#pragma unroll
                for (int i = 0; i < 4; ++i)
                    ob[(rt*16 + g*4 + i)*67 + cb*16 + r] += oacc[rt][cb][i];
    }
    __syncthreads();

    // ---- fused out-projection + bias + residual ----
    // wave wt2 handles block-local token rows wt2*16 + r, all 64 outputs
    const int orow = wt2*16 + r;
    const float inv = 1.0f / (larr[0][orow] + larr[1][orow] + larr[2][orow] + larr[3][orow]);
    bf16x8 oh_[2], ol_[2];
#pragma unroll
    for (int ks = 0; ks < 2; ++ks) {
        float ov[8];
#pragma unroll
        for (int j = 0; j < 8; ++j) {
            const int idx = orow*67 + ks*32 + g*8 + j;
            ov[j] = (otbuf[0][idx] + otbuf[1][idx]) * inv;
        }
        hilo_pack8(ov, &oh_[ks], &ol_[ks]);
    }
#pragma unroll
    for (int ot = 0; ot < 4; ++ot) {
        bf16x8 wh2[2], wl2[2];
#pragma unroll
        for (int ks = 0; ks < 2; ++ks) {
            const float* wp = wout + (size_t)(ot*16 + r) * 64 + ks*32 + g*8;
            float wv8[8];
            *(f32x4*)(wv8)     = *(const f32x4*)(wp);
            *(f32x4*)(wv8 + 4) = *(const f32x4*)(wp + 4);
            hilo_pack8(wv8, &wh2[ks], &wl2[ks]);
        }
        f32x4 a = {0.f, 0.f, 0.f, 0.f};
        a = MFMA(wh2[0], oh_[0], a);
        a = MFMA(wh2[1], oh_[1], a);
        a = MFMA(wl2[0], oh_[0], a);
        a = MFMA(wl2[1], oh_[1], a);
        a = MFMA(wh2[0], ol_[0], a);
        a = MFMA(wh2[1], ol_[1], a);
#pragma unroll
        for (int i = 0; i < 4; ++i) {
            const int oo = ot*16 + g*4 + i;
            const size_t xi = ((size_t)(b*64 + oo)) * NTOK + row0 + wt2*16 + r;
            out[xi] = a[i] + bout[oo] + x[xi];
        }
    }
}

extern "C" void kernel_launch(void* const* d_in, const int* in_sizes, int n_in,
                              void* d_out, int out_size, void* d_ws, size_t ws_size,
                              hipStream_t stream)
{
    (void)in_sizes; (void)n_in; (void)out_size; (void)ws_size;
    const float* x    = (const float*)d_in[0];
    const float* wqkv = (const float*)d_in[1];
    const float* bqkv = (const float*)d_in[2];
    const float* wout = (const float*)d_in[3];
    const float* bout = (const float*)d_in[4];
    float* out = (float*)d_out;

    char* ws = (char*)d_ws;
    const size_t MB = 1024 * 1024;
    u16* Qp = (u16*)(ws);
    u16* Kp = (u16*)(ws + 4 * MB);
    u16* Vp = (u16*)(ws + 8 * MB);

    k_qkv<<<512, 512, 0, stream>>>(x, wqkv, bqkv, Qp, Kp, Vp);
    k_attn<<<512, 256, 0, stream>>>(Qp, Kp, Vp, wout, bout, x, out);
}

// Round 18
// 55.134 us; speedup vs baseline: 1.0030x; 1.0030x over previous
//
#include <hip/hip_runtime.h>
#include <hip/hip_bf16.h>
#include <stdint.h>

typedef unsigned short u16;
typedef __attribute__((ext_vector_type(8))) short bf16x8;
typedef __attribute__((ext_vector_type(4))) float f32x4;
typedef __attribute__((ext_vector_type(2))) float f32x2;
typedef __attribute__((ext_vector_type(4))) unsigned int u32x4;
typedef __attribute__((ext_vector_type(2))) unsigned int u32x2;

#define NTOK 4096
#define NT32 32   // 4096 / 128 t2-tiles

#if __has_builtin(__builtin_amdgcn_exp2f)
#define EXP2F __builtin_amdgcn_exp2f
#else
#define EXP2F exp2f
#endif

__device__ __forceinline__ f32x4 MFMA(bf16x8 a, bf16x8 b, f32x4 c) {
    return __builtin_amdgcn_mfma_f32_16x16x32_bf16(a, b, c, 0, 0, 0);
}

// packed f32->bf16 (D.lo = bf16(a), D.hi = bf16(b))
__device__ __forceinline__ uint32_t pk_bf16(float a, float b) {
    uint32_t d;
    asm("v_cvt_pk_bf16_f32 %0, %1, %2" : "=v"(d) : "v"(a), "v"(b));
    return d;
}

// truncation hi/lo split of 8 floats into two bf16x8 fragments
__device__ __forceinline__ void hilo_pack8(const float* v, bf16x8* h, bf16x8* l) {
    union { uint32_t u[4]; bf16x8 b; } H, L;
#pragma unroll
    for (int m = 0; m < 4; ++m) {
        const uint32_t ua = __float_as_uint(v[2*m]);
        const uint32_t ub = __float_as_uint(v[2*m+1]);
        const float la = v[2*m]   - __uint_as_float(ua & 0xffff0000u);
        const float lb = v[2*m+1] - __uint_as_float(ub & 0xffff0000u);
        H.u[m] = (ua >> 16) | (ub & 0xffff0000u);
        L.u[m] = (__float_as_uint(la) >> 16) | (__float_as_uint(lb) & 0xffff0000u);
    }
    *h = H.b; *l = L.b;
}

// ---------------------------------------------------------------------------
// k_qkv: QKV projection via MFMA (w,x hi/lo 3-term) + repack through LDS.
// NOW grid 1024 (32-token tiles, 4 blocks/CU): b = blk>>7, tb = (blk&127)<<5.
// Block 256 = 4 waves; wave wv owns 48 outputs x 32 tokens (tt = 0..1).
// Phase-2: Q/K packs exactly 1 unit/thread; V-pack wtr = blk&3 (uniform).
// ---------------------------------------------------------------------------
__global__ __launch_bounds__(256) void k_qkv(
    const float* __restrict__ x, const float* __restrict__ wqkv, const float* __restrict__ bqkv,
    u16* __restrict__ Qp, u16* __restrict__ Kp, u16* __restrict__ Vp)
{
    __shared__ float qt_lds[32 * 194];
    const int blk = blockIdx.x;
    const int b   = blk >> 7;           // 0..7
    const int tb  = (blk & 127) << 5;   // 32-token tile base
    const int tid = threadIdx.x;
    const int lane = tid & 63;
    const int wv  = __builtin_amdgcn_readfirstlane(tid >> 6);
    const int r   = lane & 15;
    const int g   = lane >> 4;
    const int o0  = wv * 48;

    bf16x8 wh[3][2], wl[3][2];
#pragma unroll
    for (int oi = 0; oi < 3; ++oi)
#pragma unroll
        for (int ks = 0; ks < 2; ++ks) {
            const float* wp = wqkv + (size_t)(o0 + oi*16 + r) * 64 + ks*32 + g*8;
            float wv8[8];
            *(f32x4*)(wv8)     = *(const f32x4*)(wp);
            *(f32x4*)(wv8 + 4) = *(const f32x4*)(wp + 4);
            hilo_pack8(wv8, &wh[oi][ks], &wl[oi][ks]);
        }

    f32x4 acc[3][2];
#pragma unroll
    for (int oi = 0; oi < 3; ++oi)
#pragma unroll
        for (int tt = 0; tt < 2; ++tt) acc[oi][tt] = 0.f;

#pragma unroll
    for (int tt = 0; tt < 2; ++tt) {
        bf16x8 xh[2], xl[2];
#pragma unroll
        for (int ks = 0; ks < 2; ++ks) {
            float xv[8];
#pragma unroll
            for (int j = 0; j < 8; ++j)
                xv[j] = x[(size_t)(b*64 + ks*32 + g*8 + j) * NTOK + tb + tt*16 + r];
            hilo_pack8(xv, &xh[ks], &xl[ks]);
        }
#pragma unroll
        for (int oi = 0; oi < 3; ++oi) {
            f32x4 a = acc[oi][tt];
            a = MFMA(wh[oi][0], xh[0], a);
            a = MFMA(wh[oi][1], xh[1], a);
            a = MFMA(wl[oi][0], xh[0], a);
            a = MFMA(wl[oi][1], xh[1], a);
            a = MFMA(wh[oi][0], xl[0], a);
            a = MFMA(wh[oi][1], xl[1], a);
            acc[oi][tt] = a;
        }
    }

#pragma unroll
    for (int oi = 0; oi < 3; ++oi)
#pragma unroll
        for (int tt = 0; tt < 2; ++tt)
#pragma unroll
            for (int i = 0; i < 4; ++i)
                qt_lds[(tt*16 + r) * 194 + o0 + oi*16 + g*4 + i] = acc[oi][tt][i];
    __syncthreads();

    const float SC = 0.18033688011112042f;  // (1/8) * log2(e)

    // ---- Q pack: 1 unit/thread: t = tid>>3 (0..31), c0 = (tid&7)*8 ----
    {
        const int t = tid >> 3, c0 = (tid & 7) * 8;
        float v[8], bq[8];
#pragma unroll
        for (int m = 0; m < 4; ++m)
            *(f32x2*)(v + 2*m) = *(const f32x2*)&qt_lds[t*194 + c0 + 2*m];
        *(f32x4*)(bq)     = *(const f32x4*)(bqkv + c0);
        *(f32x4*)(bq + 4) = *(const f32x4*)(bqkv + c0 + 4);
        u32x4 P;
#pragma unroll
        for (int m = 0; m < 4; ++m)
            P[m] = pk_bf16((v[2*m] + bq[2*m]) * SC, (v[2*m+1] + bq[2*m+1]) * SC);
        *(u32x4*)(Qp + ((size_t)(b * NTOK + tb + t)) * 64 + c0) = P;
    }

    // ---- K pack: 1 unit/thread: t = tid>>3 (0..31), ks = (tid>>2)&1, gk = tid&3 ----
    {
        const int t  = tid >> 3;
        const int ks = (tid >> 2) & 1;
        const int gk = tid & 3;
        const int cb0 = 64 + ks*32 + gk*8;
        float v[8];
#pragma unroll
        for (int m = 0; m < 4; ++m)
            *(f32x2*)(v + 2*m) = *(const f32x2*)&qt_lds[t*194 + cb0 + 2*m];
        u32x4 P;
#pragma unroll
        for (int m = 0; m < 4; ++m)
            P[m] = pk_bf16(v[2*m] + bqkv[cb0 + 2*m], v[2*m+1] + bqkv[cb0 + 2*m+1]);
        const int tg = tb + t;
        // (t&15) == (tg&15) since tb is a multiple of 32
        size_t kbase = (size_t)b * 262144 + ((size_t)(tg >> 4) * 2 + ks) * 512 + gk*128 + (t & 15) * 8;
        *(u32x4*)(Kp + kbase) = P;
    }

    // ---- V pack: 2 units/thread: tq = m*4 + (tid>>6) (0..7), cb = (tid>>4)&3, r2 = tid&15 ----
    {
        const int cb = (tid >> 4) & 3;
        const int r2 = tid & 15;
        const float bv = bqkv[128 + cb*16 + r2];
        const int T128 = (blk & 127) >> 2;   // 128-token tile index
        const int wtr  = blk & 3;            // quarter = t2loc128 >> 5, uniform
#pragma unroll
        for (int m = 0; m < 2; ++m) {
            const int tq = m * 4 + (tid >> 6);   // 0..7 (quads within 32 tokens)
            float v[4];
#pragma unroll
            for (int jj = 0; jj < 4; ++jj)
                v[jj] = qt_lds[(tq*4 + jj)*194 + 128 + cb*16 + r2] + bv;
            const int t = tq * 4;                // block-local token base of quad
            const int sti = (t >> 4) & 1;
            const int g2  = (t >> 2) & 3;
            u32x2 W;
            W[0] = pk_bf16(v[0], v[1]);
            W[1] = pk_bf16(v[2], v[3]);
            size_t vbase = (size_t)b * 262144 +
                           (((size_t)T128 * 4 + wtr) * 4 + cb) * 512 + (g2*16 + r2) * 8 + sti * 4;
            *(u32x2*)(Vp + vbase) = W;
        }
    }
}

// ---------------------------------------------------------------------------
// k_attn: VERBATIM R11 (passed, 41.8 us, absmax 0.03125): K A/B register
// double-buffer, V loaded at body top, MFMA-ONES lacc, permissive (256,2).
// DO NOT: force launch_bounds (R17: numeric corruption), pair K-dbuf with
// VALU lpart (R13/R15: NaN). Occupancy here is grid-limited (2 blocks/CU).
// ---------------------------------------------------------------------------
__global__ __launch_bounds__(256, 2) void k_attn(
    const u16* __restrict__ Qp, const u16* __restrict__ Kp, const u16* __restrict__ Vp,
    const float* __restrict__ wout, const float* __restrict__ bout,
    const float* __restrict__ x, float* __restrict__ out)
{
    __shared__ float larr[4][64];
    __shared__ float otbuf[2][64 * 67];
    const int hw  = blockIdx.x;
    const int b   = hw & 7;        // batch -> XCD pinning
    const int qt  = hw >> 3;       // 0..63
    const int tid = threadIdx.x;
    const int lane = tid & 63;
    const int wt2 = tid >> 6;      // t2-slice 0..3
    const int r   = lane & 15;
    const int g   = lane >> 4;
    const int row0 = qt * 64;

    // Q fragments (B operand), rows row0 + rt*16 + r, rt = 0..3
    bf16x8 qh[4][2];
#pragma unroll
    for (int rt = 0; rt < 4; ++rt) {
        const size_t qoff = ((size_t)(b * NTOK + row0 + rt*16 + r)) * 64 + g * 8;
        qh[rt][0] = *(const bf16x8*)(Qp + qoff);
        qh[rt][1] = *(const bf16x8*)(Qp + qoff + 32);
    }

    // per-wave K/V fragment bases (tile stride 8192 elems = 16 KB)
    const u16* kbase = Kp + (size_t)b * 262144 + wt2 * 2048 + (size_t)lane * 8;
    const u16* vptr  = Vp + (size_t)b * 262144 + wt2 * 2048 + (size_t)lane * 8;

    // ones B-fragment for row-sum MFMA
    bf16x8 ONES;
#pragma unroll
    for (int j = 0; j < 8; ++j) ONES[j] = (short)0x3F80;

    f32x4 oacc[4][4];
#pragma unroll
    for (int rt = 0; rt < 4; ++rt)
#pragma unroll
        for (int cb = 0; cb < 4; ++cb) oacc[rt][cb] = 0.f;
    f32x4 lacc[4];
#pragma unroll
    for (int rt = 0; rt < 4; ++rt) lacc[rt] = 0.f;

    // preload K for tiles 0 (A) and 1 (B)
    bf16x8 kA[2][2], kB[2][2];
#pragma unroll
    for (int sti = 0; sti < 2; ++sti)
#pragma unroll
        for (int ks = 0; ks < 2; ++ks) {
            kA[sti][ks] = *(const bf16x8*)(kbase + (size_t)0*8192 + sti*1024 + ks*512);
            kB[sti][ks] = *(const bf16x8*)(kbase + (size_t)1*8192 + sti*1024 + ks*512);
        }

    auto halfrt = [&](bf16x8 (&kb)[2][2], bf16x8 (&vf)[4], int rt0) {
        // QK^T for row-tiles rt0, rt0+1 (8 MFMA)
        f32x4 s[2][2];
        __builtin_amdgcn_s_setprio(1);
#pragma unroll
        for (int rr = 0; rr < 2; ++rr)
#pragma unroll
            for (int sti = 0; sti < 2; ++sti) {
                f32x4 a = {0.f, 0.f, 0.f, 0.f};
                a = MFMA(kb[sti][0], qh[rt0 + rr][0], a);
                a = MFMA(kb[sti][1], qh[rt0 + rr][1], a);
                s[rr][sti] = a;
            }
        __builtin_amdgcn_s_setprio(0);

        // fixed-shift softmax + PV + l for the pair
#pragma unroll
        for (int rr = 0; rr < 2; ++rr) {
            const int rt = rt0 + rr;
            float p[8];
#pragma unroll
            for (int sti = 0; sti < 2; ++sti)
#pragma unroll
                for (int i = 0; i < 4; ++i)
                    p[sti*4 + i] = EXP2F(s[rr][sti][i]);
            union { uint32_t u[4]; bf16x8 b; } PA;
#pragma unroll
            for (int m = 0; m < 4; ++m) PA.u[m] = pk_bf16(p[2*m], p[2*m+1]);
            __builtin_amdgcn_s_setprio(1);
#pragma unroll
            for (int cb = 0; cb < 4; ++cb)
                oacc[rt][cb] = MFMA(PA.b, vf[cb], oacc[rt][cb]);
            lacc[rt] = MFMA(PA.b, ONES, lacc[rt]);
            __builtin_amdgcn_s_setprio(0);
        }
    };

    auto body = [&](bf16x8 (&kb)[2][2], int Tp) {
        // V fragments for this tile (consumed after QK+softmax -> self-hiding)
        bf16x8 vf[4];
#pragma unroll
        for (int cb = 0; cb < 4; ++cb)
            vf[cb] = *(const bf16x8*)(vptr + cb*512);
        vptr += 8192;

        halfrt(kb, vf, 0);
        halfrt(kb, vf, 2);

        // prefetch K for tile Tp into the register set just consumed
        const u16* kp = kbase + (size_t)Tp * 8192;
#pragma unroll
        for (int sti = 0; sti < 2; ++sti)
#pragma unroll
            for (int ks = 0; ks < 2; ++ks)
                kb[sti][ks] = *(const bf16x8*)(kp + sti*1024 + ks*512);
    };

    for (int T = 0; T < NT32; T += 2) {
        const int TpA = (T + 2 < NT32) ? T + 2 : NT32 - 1;
        const int TpB = (T + 3 < NT32) ? T + 3 : NT32 - 1;
        body(kA, TpA);
        body(kB, TpB);
    }

    // ---- epilogue: 4-way slice merge (plain sums; shift-exact softmax) ----
    if (r == 0) {
#pragma unroll
        for (int rt = 0; rt < 4; ++rt)
#pragma unroll
            for (int i = 0; i < 4; ++i)
                larr[wt2][rt*16 + g*4 + i] = lacc[rt][i];
    }

    // accumulate raw O partials (64 rows x 64 cols): wt2 0/1 write, 2/3 add
    if (wt2 < 2) {
        float* ob = otbuf[wt2];
#pragma unroll
        for (int rt = 0; rt < 4; ++rt)
#pragma unroll
            for (int cb = 0; cb < 4; ++cb)
#pragma unroll
                for (int i = 0; i < 4; ++i)
                    ob[(rt*16 + g*4 + i)*67 + cb*16 + r] = oacc[rt][cb][i];
    }
    __syncthreads();
    if (wt2 >= 2) {
        float* ob = otbuf[wt2 - 2];
#pragma unroll
        for (int rt = 0; rt < 4; ++rt)
#pragma unroll
            for (int cb = 0; cb < 4; ++cb)
#pragma unroll
                for (int i = 0; i < 4; ++i)
                    ob[(rt*16 + g*4 + i)*67 + cb*16 + r] += oacc[rt][cb][i];
    }
    __syncthreads();

    // ---- fused out-projection + bias + residual ----
    // wave wt2 handles block-local token rows wt2*16 + r, all 64 outputs
    const int orow = wt2*16 + r;
    const float inv = 1.0f / (larr[0][orow] + larr[1][orow] + larr[2][orow] + larr[3][orow]);
    bf16x8 oh_[2], ol_[2];
#pragma unroll
    for (int ks = 0; ks < 2; ++ks) {
        float ov[8];
#pragma unroll
        for (int j = 0; j < 8; ++j) {
            const int idx = orow*67 + ks*32 + g*8 + j;
            ov[j] = (otbuf[0][idx] + otbuf[1][idx]) * inv;
        }
        hilo_pack8(ov, &oh_[ks], &ol_[ks]);
    }
#pragma unroll
    for (int ot = 0; ot < 4; ++ot) {
        bf16x8 wh2[2], wl2[2];
#pragma unroll
        for (int ks = 0; ks < 2; ++ks) {
            const float* wp = wout + (size_t)(ot*16 + r) * 64 + ks*32 + g*8;
            float wv8[8];
            *(f32x4*)(wv8)     = *(const f32x4*)(wp);
            *(f32x4*)(wv8 + 4) = *(const f32x4*)(wp + 4);
            hilo_pack8(wv8, &wh2[ks], &wl2[ks]);
        }
        f32x4 a = {0.f, 0.f, 0.f, 0.f};
        a = MFMA(wh2[0], oh_[0], a);
        a = MFMA(wh2[1], oh_[1], a);
        a = MFMA(wl2[0], oh_[0], a);
        a = MFMA(wl2[1], oh_[1], a);
        a = MFMA(wh2[0], ol_[0], a);
        a = MFMA(wh2[1], ol_[1], a);
#pragma unroll
        for (int i = 0; i < 4; ++i) {
            const int oo = ot*16 + g*4 + i;
            const size_t xi = ((size_t)(b*64 + oo)) * NTOK + row0 + wt2*16 + r;
            out[xi] = a[i] + bout[oo] + x[xi];
        }
    }
}

extern "C" void kernel_launch(void* const* d_in, const int* in_sizes, int n_in,
                              void* d_out, int out_size, void* d_ws, size_t ws_size,
                              hipStream_t stream)
{
    (void)in_sizes; (void)n_in; (void)out_size; (void)ws_size;
    const float* x    = (const float*)d_in[0];
    const float* wqkv = (const float*)d_in[1];
    const float* bqkv = (const float*)d_in[2];
    const float* wout = (const float*)d_in[3];
    const float* bout = (const float*)d_in[4];
    float* out = (float*)d_out;

    char* ws = (char*)d_ws;
    const size_t MB = 1024 * 1024;
    u16* Qp = (u16*)(ws);
    u16* Kp = (u16*)(ws + 4 * MB);
    u16* Vp = (u16*)(ws + 8 * MB);

    k_qkv<<<1024, 256, 0, stream>>>(x, wqkv, bqkv, Qp, Kp, Vp);
    k_attn<<<512, 256, 0, stream>>>(Qp, Kp, Vp, wout, bout, x, out);
}

// Round 19
// 53.960 us; speedup vs baseline: 1.0248x; 1.0218x over previous
//
#include <hip/hip_runtime.h>
#include <hip/hip_bf16.h>
#include <stdint.h>

typedef unsigned short u16;
typedef __attribute__((ext_vector_type(8))) short bf16x8;
typedef __attribute__((ext_vector_type(4))) float f32x4;
typedef __attribute__((ext_vector_type(2))) float f32x2;
typedef __attribute__((ext_vector_type(4))) unsigned int u32x4;
typedef __attribute__((ext_vector_type(2))) unsigned int u32x2;

#define NTOK 4096
#define NT32 32   // 4096 / 128 t2-tiles

#if __has_builtin(__builtin_amdgcn_exp2f)
#define EXP2F __builtin_amdgcn_exp2f
#else
#define EXP2F exp2f
#endif

__device__ __forceinline__ f32x4 MFMA(bf16x8 a, bf16x8 b, f32x4 c) {
    return __builtin_amdgcn_mfma_f32_16x16x32_bf16(a, b, c, 0, 0, 0);
}

// packed f32->bf16 (D.lo = bf16(a), D.hi = bf16(b))
__device__ __forceinline__ uint32_t pk_bf16(float a, float b) {
    uint32_t d;
    asm("v_cvt_pk_bf16_f32 %0, %1, %2" : "=v"(d) : "v"(a), "v"(b));
    return d;
}

// truncation hi/lo split of 8 floats into two bf16x8 fragments
__device__ __forceinline__ void hilo_pack8(const float* v, bf16x8* h, bf16x8* l) {
    union { uint32_t u[4]; bf16x8 b; } H, L;
#pragma unroll
    for (int m = 0; m < 4; ++m) {
        const uint32_t ua = __float_as_uint(v[2*m]);
        const uint32_t ub = __float_as_uint(v[2*m+1]);
        const float la = v[2*m]   - __uint_as_float(ua & 0xffff0000u);
        const float lb = v[2*m+1] - __uint_as_float(ub & 0xffff0000u);
        H.u[m] = (ua >> 16) | (ub & 0xffff0000u);
        L.u[m] = (__float_as_uint(la) >> 16) | (__float_as_uint(lb) & 0xffff0000u);
    }
    *h = H.b; *l = L.b;
}

// ---------------------------------------------------------------------------
// k_qkv: QKV projection via MFMA (w,x hi/lo 3-term) + repack through LDS.
// R14 structure (grid 512, 256 thr, 64-token tiles) with ONE change: the
// x-tile is staged through LDS once (coalesced f32x4 coop load), so the
// MFMA loop reads x from LDS instead of 4x-redundant scalar global loads.
// xs (64 x 66 f32, 16.9 KB) ALIASES qt_lds (dead until the scatter); an
// extra __syncthreads separates last xs read from first qt write.
// ---------------------------------------------------------------------------
__global__ __launch_bounds__(256) void k_qkv(
    const float* __restrict__ x, const float* __restrict__ wqkv, const float* __restrict__ bqkv,
    u16* __restrict__ Qp, u16* __restrict__ Kp, u16* __restrict__ Vp)
{
    __shared__ float qt_lds[64 * 194];   // phase A/B: xs[c][t] stride 66 (aliased)
    const int blk = blockIdx.x;
    const int b   = blk >> 6;
    const int tb  = (blk & 63) << 6;
    const int tid = threadIdx.x;
    const int lane = tid & 63;
    const int wv  = __builtin_amdgcn_readfirstlane(tid >> 6);
    const int r   = lane & 15;
    const int g   = lane >> 4;
    const int o0  = wv * 48;

    // ---- Phase A: cooperative coalesced load of the x tile into xs ----
    {
        const int c  = tid >> 2;           // 0..63
        const int t0 = (tid & 3) * 16;     // 0,16,32,48
        const float* xp = x + (size_t)(b * 64 + c) * NTOK + tb + t0;
#pragma unroll
        for (int m = 0; m < 4; ++m) {
            f32x4 v = *(const f32x4*)(xp + 4*m);
            // stride-66 rows: 8B-aligned f32x2 stores
            *(f32x2*)&qt_lds[c*66 + t0 + 4*m]     = f32x2{v[0], v[1]};
            *(f32x2*)&qt_lds[c*66 + t0 + 4*m + 2] = f32x2{v[2], v[3]};
        }
    }

    bf16x8 wh[3][2], wl[3][2];
#pragma unroll
    for (int oi = 0; oi < 3; ++oi)
#pragma unroll
        for (int ks = 0; ks < 2; ++ks) {
            const float* wp = wqkv + (size_t)(o0 + oi*16 + r) * 64 + ks*32 + g*8;
            float wv8[8];
            *(f32x4*)(wv8)     = *(const f32x4*)(wp);
            *(f32x4*)(wv8 + 4) = *(const f32x4*)(wp + 4);
            hilo_pack8(wv8, &wh[oi][ks], &wl[oi][ks]);
        }
    __syncthreads();   // xs ready

    f32x4 acc[3][4];
#pragma unroll
    for (int oi = 0; oi < 3; ++oi)
#pragma unroll
        for (int tt = 0; tt < 4; ++tt) acc[oi][tt] = 0.f;

#pragma unroll
    for (int tt = 0; tt < 4; ++tt) {
        bf16x8 xh[2], xl[2];
#pragma unroll
        for (int ks = 0; ks < 2; ++ks) {
            float xv[8];
#pragma unroll
            for (int j = 0; j < 8; ++j)
                xv[j] = qt_lds[(ks*32 + g*8 + j)*66 + tt*16 + r];
            hilo_pack8(xv, &xh[ks], &xl[ks]);
        }
#pragma unroll
        for (int oi = 0; oi < 3; ++oi) {
            f32x4 a = acc[oi][tt];
            a = MFMA(wh[oi][0], xh[0], a);
            a = MFMA(wh[oi][1], xh[1], a);
            a = MFMA(wl[oi][0], xh[0], a);
            a = MFMA(wl[oi][1], xh[1], a);
            a = MFMA(wh[oi][0], xl[0], a);
            a = MFMA(wh[oi][1], xl[1], a);
            acc[oi][tt] = a;
        }
    }
    __syncthreads();   // all xs reads done before overwriting the buffer

#pragma unroll
    for (int oi = 0; oi < 3; ++oi)
#pragma unroll
        for (int tt = 0; tt < 4; ++tt)
#pragma unroll
            for (int i = 0; i < 4; ++i)
                qt_lds[(tt*16 + r) * 194 + o0 + oi*16 + g*4 + i] = acc[oi][tt][i];
    __syncthreads();

    const float SC = 0.18033688011112042f;  // (1/8) * log2(e)

    {
        const int t = tid >> 2, c0 = (tid & 3) * 16;
        float v[16], bq[16];
#pragma unroll
        for (int m = 0; m < 8; ++m)
            *(f32x2*)(v + 2*m) = *(const f32x2*)&qt_lds[t*194 + c0 + 2*m];
#pragma unroll
        for (int m = 0; m < 4; ++m)
            *(f32x4*)(bq + 4*m) = *(const f32x4*)(bqkv + c0 + 4*m);
        u32x4 P0, P1;
#pragma unroll
        for (int m = 0; m < 4; ++m) {
            P0[m] = pk_bf16((v[2*m]   + bq[2*m]  ) * SC, (v[2*m+1] + bq[2*m+1]) * SC);
            P1[m] = pk_bf16((v[8+2*m] + bq[8+2*m]) * SC, (v[9+2*m] + bq[9+2*m]) * SC);
        }
        size_t base = ((size_t)(b * NTOK + tb + t)) * 64 + c0;
        *(u32x4*)(Qp + base)     = P0;
        *(u32x4*)(Qp + base + 8) = P1;
    }

#pragma unroll
    for (int uu = 0; uu < 2; ++uu) {
        const int u  = tid * 2 + uu;
        const int t  = u >> 3;
        const int ks = (u >> 2) & 1;
        const int gk = u & 3;
        const int cb0 = 64 + ks*32 + gk*8;
        float v[8];
#pragma unroll
        for (int m = 0; m < 4; ++m)
            *(f32x2*)(v + 2*m) = *(const f32x2*)&qt_lds[t*194 + cb0 + 2*m];
        u32x4 P;
#pragma unroll
        for (int m = 0; m < 4; ++m)
            P[m] = pk_bf16(v[2*m] + bqkv[cb0 + 2*m], v[2*m+1] + bqkv[cb0 + 2*m+1]);
        const int tg = tb + t;
        size_t kbase = (size_t)b * 262144 + ((size_t)(tg >> 4) * 2 + ks) * 512 + gk*128 + (t & 15) * 8;
        *(u32x4*)(Kp + kbase) = P;
    }

    {
        const int cb = (tid >> 4) & 3;
        const int r2 = tid & 15;
        const float bv = bqkv[128 + cb*16 + r2];
        const int T = (blk & 63) >> 1;
        const int halfb = blk & 1;
#pragma unroll
        for (int m = 0; m < 4; ++m) {
            const int tq = m * 4 + (tid >> 6);
            float v[4];
#pragma unroll
            for (int jj = 0; jj < 4; ++jj)
                v[jj] = qt_lds[(tq*4 + jj)*194 + 128 + cb*16 + r2] + bv;
            const int t = tq * 4;
            const int wtr = halfb*2 + (t >> 5);
            const int sti = (t >> 4) & 1;
            const int g2  = (t >> 2) & 3;
            u32x2 W;
            W[0] = pk_bf16(v[0], v[1]);
            W[1] = pk_bf16(v[2], v[3]);
            size_t vbase = (size_t)b * 262144 +
                           (((size_t)T * 4 + wtr) * 4 + cb) * 512 + (g2*16 + r2) * 8 + sti * 4;
            *(u32x2*)(Vp + vbase) = W;
        }
    }
}

// ---------------------------------------------------------------------------
// k_attn: VERBATIM R11 (passed, 41.8 us, absmax 0.03125): K A/B register
// double-buffer, V loaded at body top, MFMA-ONES lacc, permissive (256,2).
// DO NOT: force launch_bounds (R17: numeric corruption), pair K-dbuf with
// VALU lpart (R13/R15: NaN). Occupancy here is grid-limited (2 blocks/CU).
// ---------------------------------------------------------------------------
__global__ __launch_bounds__(256, 2) void k_attn(
    const u16* __restrict__ Qp, const u16* __restrict__ Kp, const u16* __restrict__ Vp,
    const float* __restrict__ wout, const float* __restrict__ bout,
    const float* __restrict__ x, float* __restrict__ out)
{
    __shared__ float larr[4][64];
    __shared__ float otbuf[2][64 * 67];
    const int hw  = blockIdx.x;
    const int b   = hw & 7;        // batch -> XCD pinning
    const int qt  = hw >> 3;       // 0..63
    const int tid = threadIdx.x;
    const int lane = tid & 63;
    const int wt2 = tid >> 6;      // t2-slice 0..3
    const int r   = lane & 15;
    const int g   = lane >> 4;
    const int row0 = qt * 64;

    // Q fragments (B operand), rows row0 + rt*16 + r, rt = 0..3
    bf16x8 qh[4][2];
#pragma unroll
    for (int rt = 0; rt < 4; ++rt) {
        const size_t qoff = ((size_t)(b * NTOK + row0 + rt*16 + r)) * 64 + g * 8;
        qh[rt][0] = *(const bf16x8*)(Qp + qoff);
        qh[rt][1] = *(const bf16x8*)(Qp + qoff + 32);
    }

    // per-wave K/V fragment bases (tile stride 8192 elems = 16 KB)
    const u16* kbase = Kp + (size_t)b * 262144 + wt2 * 2048 + (size_t)lane * 8;
    const u16* vptr  = Vp + (size_t)b * 262144 + wt2 * 2048 + (size_t)lane * 8;

    // ones B-fragment for row-sum MFMA
    bf16x8 ONES;
#pragma unroll
    for (int j = 0; j < 8; ++j) ONES[j] = (short)0x3F80;

    f32x4 oacc[4][4];
#pragma unroll
    for (int rt = 0; rt < 4; ++rt)
#pragma unroll
        for (int cb = 0; cb < 4; ++cb) oacc[rt][cb] = 0.f;
    f32x4 lacc[4];
#pragma unroll
    for (int rt = 0; rt < 4; ++rt) lacc[rt] = 0.f;

    // preload K for tiles 0 (A) and 1 (B)
    bf16x8 kA[2][2], kB[2][2];
#pragma unroll
    for (int sti = 0; sti < 2; ++sti)
#pragma unroll
        for (int ks = 0; ks < 2; ++ks) {
            kA[sti][ks] = *(const bf16x8*)(kbase + (size_t)0*8192 + sti*1024 + ks*512);
            kB[sti][ks] = *(const bf16x8*)(kbase + (size_t)1*8192 + sti*1024 + ks*512);
        }

    auto halfrt = [&](bf16x8 (&kb)[2][2], bf16x8 (&vf)[4], int rt0) {
        // QK^T for row-tiles rt0, rt0+1 (8 MFMA)
        f32x4 s[2][2];
        __builtin_amdgcn_s_setprio(1);
#pragma unroll
        for (int rr = 0; rr < 2; ++rr)
#pragma unroll
            for (int sti = 0; sti < 2; ++sti) {
                f32x4 a = {0.f, 0.f, 0.f, 0.f};
                a = MFMA(kb[sti][0], qh[rt0 + rr][0], a);
                a = MFMA(kb[sti][1], qh[rt0 + rr][1], a);
                s[rr][sti] = a;
            }
        __builtin_amdgcn_s_setprio(0);

        // fixed-shift softmax + PV + l for the pair
#pragma unroll
        for (int rr = 0; rr < 2; ++rr) {
            const int rt = rt0 + rr;
            float p[8];
#pragma unroll
            for (int sti = 0; sti < 2; ++sti)
#pragma unroll
                for (int i = 0; i < 4; ++i)
                    p[sti*4 + i] = EXP2F(s[rr][sti][i]);
            union { uint32_t u[4]; bf16x8 b; } PA;
#pragma unroll
            for (int m = 0; m < 4; ++m) PA.u[m] = pk_bf16(p[2*m], p[2*m+1]);
            __builtin_amdgcn_s_setprio(1);
#pragma unroll
            for (int cb = 0; cb < 4; ++cb)
                oacc[rt][cb] = MFMA(PA.b, vf[cb], oacc[rt][cb]);
            lacc[rt] = MFMA(PA.b, ONES, lacc[rt]);
            __builtin_amdgcn_s_setprio(0);
        }
    };

    auto body = [&](bf16x8 (&kb)[2][2], int Tp) {
        // V fragments for this tile (consumed after QK+softmax -> self-hiding)
        bf16x8 vf[4];
#pragma unroll
        for (int cb = 0; cb < 4; ++cb)
            vf[cb] = *(const bf16x8*)(vptr + cb*512);
        vptr += 8192;

        halfrt(kb, vf, 0);
        halfrt(kb, vf, 2);

        // prefetch K for tile Tp into the register set just consumed
        const u16* kp = kbase + (size_t)Tp * 8192;
#pragma unroll
        for (int sti = 0; sti < 2; ++sti)
#pragma unroll
            for (int ks = 0; ks < 2; ++ks)
                kb[sti][ks] = *(const bf16x8*)(kp + sti*1024 + ks*512);
    };

    for (int T = 0; T < NT32; T += 2) {
        const int TpA = (T + 2 < NT32) ? T + 2 : NT32 - 1;
        const int TpB = (T + 3 < NT32) ? T + 3 : NT32 - 1;
        body(kA, TpA);
        body(kB, TpB);
    }

    // ---- epilogue: 4-way slice merge (plain sums; shift-exact softmax) ----
    if (r == 0) {
#pragma unroll
        for (int rt = 0; rt < 4; ++rt)
#pragma unroll
            for (int i = 0; i < 4; ++i)
                larr[wt2][rt*16 + g*4 + i] = lacc[rt][i];
    }

    // accumulate raw O partials (64 rows x 64 cols): wt2 0/1 write, 2/3 add
    if (wt2 < 2) {
        float* ob = otbuf[wt2];
#pragma unroll
        for (int rt = 0; rt < 4; ++rt)
#pragma unroll
            for (int cb = 0; cb < 4; ++cb)
#pragma unroll
                for (int i = 0; i < 4; ++i)
                    ob[(rt*16 + g*4 + i)*67 + cb*16 + r] = oacc[rt][cb][i];
    }
    __syncthreads();
    if (wt2 >= 2) {
        float* ob = otbuf[wt2 - 2];
#pragma unroll
        for (int rt = 0; rt < 4; ++rt)
#pragma unroll
            for (int cb = 0; cb < 4; ++cb)
#pragma unroll
                for (int i = 0; i < 4; ++i)
                    ob[(rt*16 + g*4 + i)*67 + cb*16 + r] += oacc[rt][cb][i];
    }
    __syncthreads();

    // ---- fused out-projection + bias + residual ----
    // wave wt2 handles block-local token rows wt2*16 + r, all 64 outputs
    const int orow = wt2*16 + r;
    const float inv = 1.0f / (larr[0][orow] + larr[1][orow] + larr[2][orow] + larr[3][orow]);
    bf16x8 oh_[2], ol_[2];
#pragma unroll
    for (int ks = 0; ks < 2; ++ks) {
        float ov[8];
#pragma unroll
        for (int j = 0; j < 8; ++j) {
            const int idx = orow*67 + ks*32 + g*8 + j;
            ov[j] = (otbuf[0][idx] + otbuf[1][idx]) * inv;
        }
        hilo_pack8(ov, &oh_[ks], &ol_[ks]);
    }
#pragma unroll
    for (int ot = 0; ot < 4; ++ot) {
        bf16x8 wh2[2], wl2[2];
#pragma unroll
        for (int ks = 0; ks < 2; ++ks) {
            const float* wp = wout + (size_t)(ot*16 + r) * 64 + ks*32 + g*8;
            float wv8[8];
            *(f32x4*)(wv8)     = *(const f32x4*)(wp);
            *(f32x4*)(wv8 + 4) = *(const f32x4*)(wp + 4);
            hilo_pack8(wv8, &wh2[ks], &wl2[ks]);
        }
        f32x4 a = {0.f, 0.f, 0.f, 0.f};
        a = MFMA(wh2[0], oh_[0], a);
        a = MFMA(wh2[1], oh_[1], a);
        a = MFMA(wl2[0], oh_[0], a);
        a = MFMA(wl2[1], oh_[1], a);
        a = MFMA(wh2[0], ol_[0], a);
        a = MFMA(wh2[1], ol_[1], a);
#pragma unroll
        for (int i = 0; i < 4; ++i) {
            const int oo = ot*16 + g*4 + i;
            const size_t xi = ((size_t)(b*64 + oo)) * NTOK + row0 + wt2*16 + r;
            out[xi] = a[i] + bout[oo] + x[xi];
        }
    }
}

extern "C" void kernel_launch(void* const* d_in, const int* in_sizes, int n_in,
                              void* d_out, int out_size, void* d_ws, size_t ws_size,
                              hipStream_t stream)
{
    (void)in_sizes; (void)n_in; (void)out_size; (void)ws_size;
    const float* x    = (const float*)d_in[0];
    const float* wqkv = (const float*)d_in[1];
    const float* bqkv = (const float*)d_in[2];
    const float* wout = (const float*)d_in[3];
    const float* bout = (const float*)d_in[4];
    float* out = (float*)d_out;

    char* ws = (char*)d_ws;
    const size_t MB = 1024 * 1024;
    u16* Qp = (u16*)(ws);
    u16* Kp = (u16*)(ws + 4 * MB);
    u16* Vp = (u16*)(ws + 8 * MB);

    k_qkv<<<512, 256, 0, stream>>>(x, wqkv, bqkv, Qp, Kp, Vp);
    k_attn<<<512, 256, 0, stream>>>(Qp, Kp, Vp, wout, bout, x, out);
}